// Round 9
// baseline (56.631 us; speedup 1.0000x reference)
//
#include <hip/hip_runtime.h>
#include <stdint.h>

namespace {

constexpr int kB = 32, kS = 8, kT = 1024, kF = 128;
constexpr int kBS = kB * kS;          // 256
constexpr int kSlice = kT * kF;       // 131072 elements per (b,s)
constexpr uint32_t kSpanT = 122;      // randint(1, 123) span
constexpr uint32_t kSpanF = 15;       // randint(1, 16)  span

typedef float f32x4 __attribute__((ext_vector_type(4)));

struct BSParams {
  int ts1, te1, ts2, te2;   // time-mask intervals [s,e) (apply folded: e==s when not applied)
  int fs1, fe1, fs2, fe2;   // freq-mask intervals
  float scale;
  int apply_n;
  uint32_t kn0, kn1;        // noise key
};  // 48 bytes

__device__ __forceinline__ uint32_t rotl32(uint32_t v, int d) {
  return (v << d) | (v >> (32 - d));
}

// Threefry-2x32, 20 rounds (JAX-compatible).
__device__ __forceinline__ void tf2x32(uint32_t k0, uint32_t k1, uint32_t x0, uint32_t x1,
                                       uint32_t& o0, uint32_t& o1) {
  const uint32_t ks0 = k0, ks1 = k1, ks2 = k0 ^ k1 ^ 0x1BD11BDAu;
  x0 += ks0; x1 += ks1;
  x0 += x1; x1 = rotl32(x1, 13); x1 ^= x0;
  x0 += x1; x1 = rotl32(x1, 15); x1 ^= x0;
  x0 += x1; x1 = rotl32(x1, 26); x1 ^= x0;
  x0 += x1; x1 = rotl32(x1, 6);  x1 ^= x0;
  x0 += ks1; x1 += ks2 + 1u;
  x0 += x1; x1 = rotl32(x1, 17); x1 ^= x0;
  x0 += x1; x1 = rotl32(x1, 29); x1 ^= x0;
  x0 += x1; x1 = rotl32(x1, 16); x1 ^= x0;
  x0 += x1; x1 = rotl32(x1, 24); x1 ^= x0;
  x0 += ks2; x1 += ks0 + 2u;
  x0 += x1; x1 = rotl32(x1, 13); x1 ^= x0;
  x0 += x1; x1 = rotl32(x1, 15); x1 ^= x0;
  x0 += x1; x1 = rotl32(x1, 26); x1 ^= x0;
  x0 += x1; x1 = rotl32(x1, 6);  x1 ^= x0;
  x0 += ks0; x1 += ks1 + 3u;
  x0 += x1; x1 = rotl32(x1, 17); x1 ^= x0;
  x0 += x1; x1 = rotl32(x1, 29); x1 ^= x0;
  x0 += x1; x1 = rotl32(x1, 16); x1 ^= x0;
  x0 += x1; x1 = rotl32(x1, 24); x1 ^= x0;
  x0 += ks1; x1 += ks2 + 4u;
  x0 += x1; x1 = rotl32(x1, 13); x1 ^= x0;
  x0 += x1; x1 = rotl32(x1, 15); x1 ^= x0;
  x0 += x1; x1 = rotl32(x1, 26); x1 ^= x0;
  x0 += x1; x1 = rotl32(x1, 6);  x1 ^= x0;
  x0 += ks2; x1 += ks0 + 5u;
  o0 = x0; o1 = x1;
}

// Partitionable-mode random bits (32-bit) at flat counter i: xor of both output words.
__device__ __forceinline__ uint32_t bits32(uint32_t k0, uint32_t k1, uint32_t ctr) {
  uint32_t o0, o1;
  tf2x32(k0, k1, 0u, ctr, o0, o1);
  return o0 ^ o1;
}

// uniform [0,1) from 32 random bits, JAX-style.
__device__ __forceinline__ float u01(uint32_t bits) {
  return __uint_as_float(0x3f800000u | (bits >> 9)) - 1.0f;
}

// Fast erfinv: Giles main poly with hardware log, branchless 2-term tail.
// Tail fit err <= 0.011 over w in [5,16.6] -> <=0.001 on the final output (budget 0.113).
__device__ __forceinline__ float erfinv_fast(float x) {
  float t = fmaf(-x, x, 1.0f);                          // 1 - x^2 (fma: no cancellation)
  float w = -0.69314718f * __builtin_amdgcn_logf(t);    // -ln(1-x^2)
  float wm = w - 2.5f;
  float p = 2.81022636e-08f;
  p = fmaf(p, wm, 3.43273939e-07f);
  p = fmaf(p, wm, -3.5233877e-06f);
  p = fmaf(p, wm, -4.39150654e-06f);
  p = fmaf(p, wm, 0.00021858087f);
  p = fmaf(p, wm, -0.00125372503f);
  p = fmaf(p, wm, -0.00417768164f);
  p = fmaf(p, wm, 0.246640727f);
  p = fmaf(p, wm, 1.50140941f);
  float tail = fmaf(1.0003f, __builtin_amdgcn_sqrtf(w), -0.1623f);
  p = (w < 5.0f) ? p : tail;
  return p * x;
}

// One _axis_mask's per-(b,s) params: split(K,3) -> k1(randint),k2(uniform start),k3(apply).
__device__ void axis_params(uint32_t K0, uint32_t K1, int dim, uint32_t span, uint32_t i,
                            int& start_out, int& end_out) {
  uint32_t k10, k11, k20, k21, k30, k31, a0, a1, b0, b1;
  tf2x32(K0, K1, 0u, 0u, k10, k11);   // k1
  tf2x32(K0, K1, 0u, 1u, k20, k21);   // k2
  tf2x32(K0, K1, 0u, 2u, k30, k31);   // k3
  tf2x32(k10, k11, 0u, 0u, a0, a1);   // randint internal split
  tf2x32(k10, k11, 0u, 1u, b0, b1);
  uint32_t hi = bits32(a0, a1, i);
  uint32_t lo = bits32(b0, b1, i);
  uint32_t mult = 65536u % span;
  mult = (mult * mult) % span;
  uint32_t off = ((hi % span) * mult + (lo % span)) % span;
  int width = 1 + (int)off;
  float u = u01(bits32(k20, k21, i));
  int M = dim - width; if (M < 1) M = 1;
  int start = (int)floorf(u * (float)M);
  bool apply = u01(bits32(k30, k31, i)) > 0.35f;
  start_out = start;
  end_out = apply ? (start + width) : start;   // empty interval when not applied
}

// Fallback (no workspace): full per-(b,s) params in one thread.
__device__ BSParams compute_params(uint32_t i) {
  BSParams p;
  uint32_t w0, w1;
  tf2x32(0u, 42u, 0u, 0u, w0, w1); axis_params(w0, w1, kT, kSpanT, i, p.ts1, p.te1);  // kt1
  tf2x32(0u, 42u, 0u, 1u, w0, w1); axis_params(w0, w1, kT, kSpanT, i, p.ts2, p.te2);  // kt2
  tf2x32(0u, 42u, 0u, 2u, w0, w1); axis_params(w0, w1, kF, kSpanF, i, p.fs1, p.fe1);  // kf1
  tf2x32(0u, 42u, 0u, 3u, w0, w1); axis_params(w0, w1, kF, kSpanF, i, p.fs2, p.fe2);  // kf2
  tf2x32(0u, 42u, 0u, 4u, w0, w1);                                                    // kn_a
  p.apply_n = (u01(bits32(w0, w1, i)) > 0.45f) ? 1 : 0;
  tf2x32(0u, 42u, 0u, 5u, p.kn0, p.kn1);                                              // kn
  tf2x32(0u, 42u, 0u, 6u, w0, w1);                                                    // ks_a
  bool apply_s = u01(bits32(w0, w1, i)) > 0.5f;
  tf2x32(0u, 42u, 0u, 7u, w0, w1);                                                    // ks
  float su = u01(bits32(w0, w1, i));
  float sc = fmaxf(0.85f, fmaf(su, 1.15f - 0.85f, 0.85f));
  p.scale = apply_s ? sc : 1.0f;
  return p;
}

// 4-wide parallel params: 1024 threads = 256 bs x 4 units; LDS combine.
__global__ __launch_bounds__(1024) void spec_params_kernel(BSParams* __restrict__ P) {
  __shared__ BSParams sp[kBS];
  __shared__ float ssc[kBS];
  __shared__ int ssa[kBS];
  const uint32_t bs = threadIdx.x & 255u;
  const uint32_t unit = threadIdx.x >> 8;   // 0..3
  uint32_t w0, w1;
  tf2x32(0u, 42u, 0u, unit, w0, w1);        // subkey for this unit's axis
  int s, e;
  if (unit < 2) axis_params(w0, w1, kT, kSpanT, bs, s, e);
  else          axis_params(w0, w1, kF, kSpanF, bs, s, e);
  if (unit == 0) { sp[bs].ts1 = s; sp[bs].te1 = e; }
  else if (unit == 1) { sp[bs].ts2 = s; sp[bs].te2 = e; }
  else if (unit == 2) { sp[bs].fs1 = s; sp[bs].fe1 = e; }
  else { sp[bs].fs2 = s; sp[bs].fe2 = e; }
  // cheap items spread one per unit
  if (unit == 0) {
    tf2x32(0u, 42u, 0u, 4u, w0, w1);                       // kn_a
    sp[bs].apply_n = (u01(bits32(w0, w1, bs)) > 0.45f) ? 1 : 0;
  } else if (unit == 1) {
    uint32_t n0, n1;
    tf2x32(0u, 42u, 0u, 5u, n0, n1);                       // kn
    sp[bs].kn0 = n0; sp[bs].kn1 = n1;
  } else if (unit == 2) {
    tf2x32(0u, 42u, 0u, 6u, w0, w1);                       // ks_a
    ssa[bs] = (u01(bits32(w0, w1, bs)) > 0.5f) ? 1 : 0;
  } else {
    tf2x32(0u, 42u, 0u, 7u, w0, w1);                       // ks
    float su = u01(bits32(w0, w1, bs));
    ssc[bs] = fmaxf(0.85f, fmaf(su, 1.15f - 0.85f, 0.85f));
  }
  __syncthreads();
  if (unit == 0) {
    sp[bs].scale = ssa[bs] ? ssc[bs] : 1.0f;
    P[bs] = sp[bs];
  }
}

// Round-4 structure: grid (32, 256), y = bs slowest (locality-preserving).
// Block covers 4096 elems of one (b,s) slice as 4 coalesced chunks of 1024;
// thread owns 4 floats per chunk (16 B/lane -> 1 KiB/wave per instruction).
// A/B vs round 8: plain (L2-allocating, write-combining) stores instead of nt.
template <bool USE_WS>
__global__ __launch_bounds__(256) void spec_main_kernel(const float* __restrict__ specs,
                                                        const int* __restrict__ mask,
                                                        float* __restrict__ out,
                                                        const BSParams* __restrict__ P) {
  const int bs = blockIdx.y;                           // 0..255
  const int block_off = blockIdx.x * 4096;             // within slice
  const int tid4 = threadIdx.x * 4;
  const long slice_base = (long)bs * kSlice;

  f32x4 a[4];
  long base[4];
#pragma unroll
  for (int k = 0; k < 4; ++k) {
    base[k] = slice_base + block_off + k * 1024 + tid4;
    a[k] = *reinterpret_cast<const f32x4*>(specs + base[k]);
  }

  if (mask[bs] == 0) {  // sensor off: pure passthrough (uniform per block)
#pragma unroll
    for (int k = 0; k < 4; ++k)
      *reinterpret_cast<f32x4*>(out + base[k]) = a[k];
    return;
  }

  BSParams p;
  if (USE_WS) p = P[bs]; else p = compute_params((uint32_t)bs);

  // f-part of keep mask is chunk-invariant: off & 127 == tid4 & 127 for all chunks.
  const int f0 = tid4 & 127;
  int lo1 = min(4, max(0, p.fs1 - f0)), hi1 = min(4, max(0, p.fe1 - f0));
  int lo2 = min(4, max(0, p.fs2 - f0)), hi2 = min(4, max(0, p.fe2 - f0));
  uint32_t z1 = ((1u << hi1) - 1u) & ~((1u << lo1) - 1u);
  uint32_t z2 = ((1u << hi2) - 1u) & ~((1u << lo2) - 1u);
  const uint32_t fkeep = 0xFu & ~(z1 | z2);

  const int t0 = (block_off + tid4) >> 7;              // chunk k: t = t0 + 8k
  const float LO = __int_as_float(0xBF7FFFFF);         // nextafter(-1, 0)
  const float sc = p.scale;

  if (p.apply_n) {   // uniform per block
#pragma unroll
    for (int k = 0; k < 4; ++k) {
      const int t = t0 + k * 8;
      const bool tm = !((t >= p.ts1) & (t < p.te1)) && !((t >= p.ts2) & (t < p.te2));
      const uint32_t keep = tm ? fkeep : 0u;
      const uint32_t c0 = (uint32_t)base[k];
      // data-independent noise first: overlaps threefry with in-flight loads
      float nv[4];
#pragma unroll
      for (int j = 0; j < 4; ++j) {
        const uint32_t bits = bits32(p.kn0, p.kn1, c0 + (uint32_t)j);
        float u1 = __uint_as_float(0x3f800000u | (bits >> 9));   // [1,2)
        float x = fmaxf(LO, fmaf(u1, 2.0f, -2.0f) + LO);         // == (u1-1)*2 + LO
        nv[j] = 0.08485281374f * erfinv_fast(x);                 // 0.06*sqrt(2)*erfinv
      }
      float v[4] = {a[k].x, a[k].y, a[k].z, a[k].w};
#pragma unroll
      for (int j = 0; j < 4; ++j) {
        float s = ((keep & (1u << j)) ? v[j] : 0.0f) + nv[j];
        s *= sc;
        v[j] = fminf(10.0f, fmaxf(-10.0f, s));
      }
      f32x4 r = {v[0], v[1], v[2], v[3]};
      *reinterpret_cast<f32x4*>(out + base[k]) = r;
    }
  } else {
#pragma unroll
    for (int k = 0; k < 4; ++k) {
      const int t = t0 + k * 8;
      const bool tm = !((t >= p.ts1) & (t < p.te1)) && !((t >= p.ts2) & (t < p.te2));
      const uint32_t keep = tm ? fkeep : 0u;
      float v[4] = {a[k].x, a[k].y, a[k].z, a[k].w};
#pragma unroll
      for (int j = 0; j < 4; ++j) {
        float s = (keep & (1u << j)) ? v[j] : 0.0f;
        s *= sc;
        v[j] = fminf(10.0f, fmaxf(-10.0f, s));
      }
      f32x4 r = {v[0], v[1], v[2], v[3]};
      *reinterpret_cast<f32x4*>(out + base[k]) = r;
    }
  }
}

}  // namespace

extern "C" void kernel_launch(void* const* d_in, const int* in_sizes, int n_in,
                              void* d_out, int out_size, void* d_ws, size_t ws_size,
                              hipStream_t stream) {
  const float* specs = (const float*)d_in[0];
  const int* mask = (const int*)d_in[1];
  float* out = (float*)d_out;

  dim3 grid(kSlice / 4096, kBS);  // (32, 256), y = bs slowest
  dim3 block(256);

  if (ws_size >= sizeof(BSParams) * kBS) {
    BSParams* P = (BSParams*)d_ws;
    hipLaunchKernelGGL(spec_params_kernel, dim3(1), dim3(1024), 0, stream, P);
    hipLaunchKernelGGL((spec_main_kernel<true>), grid, block, 0, stream, specs, mask, out, P);
  } else {
    hipLaunchKernelGGL((spec_main_kernel<false>), grid, block, 0, stream, specs, mask, out,
                       (const BSParams*)nullptr);
  }
}

// Round 10
// 55.891 us; speedup vs baseline: 1.0132x; 1.0132x over previous
//
#include <hip/hip_runtime.h>
#include <stdint.h>

namespace {

constexpr int kB = 32, kS = 8, kT = 1024, kF = 128;
constexpr int kBS = kB * kS;          // 256
constexpr int kSlice = kT * kF;       // 131072 elements per (b,s)
constexpr uint32_t kSpanT = 122;      // randint(1, 123) span
constexpr uint32_t kSpanF = 15;       // randint(1, 16)  span

typedef float f32x4 __attribute__((ext_vector_type(4)));

struct BSParams {
  int ts1, te1, ts2, te2;   // time-mask intervals [s,e) (apply folded: e==s when not applied)
  int fs1, fe1, fs2, fe2;   // freq-mask intervals
  float scale;
  int apply_n;
  uint32_t kn0, kn1;        // noise key
};  // 48 bytes

// Batched streaming stores: nt (non-temporal) + sc1 (system scope / no-allocate in
// memory-side cache). The trailing s_waitcnt expcnt(0) guarantees the store unit has
// consumed all data/address VGPRs before the asm block ends, so the compiler's
// register reuse after the block is safe (round 7's corruption was this hazard).
__device__ __forceinline__ void store4_nt_sc1(float* a0, f32x4 v0, float* a1, f32x4 v1,
                                              float* a2, f32x4 v2, float* a3, f32x4 v3) {
  asm volatile(
      "global_store_dwordx4 %0, %4, off nt sc1\n\t"
      "global_store_dwordx4 %1, %5, off nt sc1\n\t"
      "global_store_dwordx4 %2, %6, off nt sc1\n\t"
      "global_store_dwordx4 %3, %7, off nt sc1\n\t"
      "s_waitcnt expcnt(0)"
      :: "v"(a0), "v"(a1), "v"(a2), "v"(a3),
         "v"(v0), "v"(v1), "v"(v2), "v"(v3)
      : "memory");
}

__device__ __forceinline__ uint32_t rotl32(uint32_t v, int d) {
  return (v << d) | (v >> (32 - d));
}

// Threefry-2x32, 20 rounds (JAX-compatible).
__device__ __forceinline__ void tf2x32(uint32_t k0, uint32_t k1, uint32_t x0, uint32_t x1,
                                       uint32_t& o0, uint32_t& o1) {
  const uint32_t ks0 = k0, ks1 = k1, ks2 = k0 ^ k1 ^ 0x1BD11BDAu;
  x0 += ks0; x1 += ks1;
  x0 += x1; x1 = rotl32(x1, 13); x1 ^= x0;
  x0 += x1; x1 = rotl32(x1, 15); x1 ^= x0;
  x0 += x1; x1 = rotl32(x1, 26); x1 ^= x0;
  x0 += x1; x1 = rotl32(x1, 6);  x1 ^= x0;
  x0 += ks1; x1 += ks2 + 1u;
  x0 += x1; x1 = rotl32(x1, 17); x1 ^= x0;
  x0 += x1; x1 = rotl32(x1, 29); x1 ^= x0;
  x0 += x1; x1 = rotl32(x1, 16); x1 ^= x0;
  x0 += x1; x1 = rotl32(x1, 24); x1 ^= x0;
  x0 += ks2; x1 += ks0 + 2u;
  x0 += x1; x1 = rotl32(x1, 13); x1 ^= x0;
  x0 += x1; x1 = rotl32(x1, 15); x1 ^= x0;
  x0 += x1; x1 = rotl32(x1, 26); x1 ^= x0;
  x0 += x1; x1 = rotl32(x1, 6);  x1 ^= x0;
  x0 += ks0; x1 += ks1 + 3u;
  x0 += x1; x1 = rotl32(x1, 17); x1 ^= x0;
  x0 += x1; x1 = rotl32(x1, 29); x1 ^= x0;
  x0 += x1; x1 = rotl32(x1, 16); x1 ^= x0;
  x0 += x1; x1 = rotl32(x1, 24); x1 ^= x0;
  x0 += ks1; x1 += ks2 + 4u;
  x0 += x1; x1 = rotl32(x1, 13); x1 ^= x0;
  x0 += x1; x1 = rotl32(x1, 15); x1 ^= x0;
  x0 += x1; x1 = rotl32(x1, 26); x1 ^= x0;
  x0 += x1; x1 = rotl32(x1, 6);  x1 ^= x0;
  x0 += ks2; x1 += ks0 + 5u;
  o0 = x0; o1 = x1;
}

// Partitionable-mode random bits (32-bit) at flat counter i: xor of both output words.
__device__ __forceinline__ uint32_t bits32(uint32_t k0, uint32_t k1, uint32_t ctr) {
  uint32_t o0, o1;
  tf2x32(k0, k1, 0u, ctr, o0, o1);
  return o0 ^ o1;
}

// uniform [0,1) from 32 random bits, JAX-style.
__device__ __forceinline__ float u01(uint32_t bits) {
  return __uint_as_float(0x3f800000u | (bits >> 9)) - 1.0f;
}

// Fast erfinv: Giles main poly with hardware log, branchless 2-term tail.
// Tail fit err <= 0.011 over w in [5,16.6] -> <=0.001 on the final output (budget 0.113).
__device__ __forceinline__ float erfinv_fast(float x) {
  float t = fmaf(-x, x, 1.0f);                          // 1 - x^2 (fma: no cancellation)
  float w = -0.69314718f * __builtin_amdgcn_logf(t);    // -ln(1-x^2)
  float wm = w - 2.5f;
  float p = 2.81022636e-08f;
  p = fmaf(p, wm, 3.43273939e-07f);
  p = fmaf(p, wm, -3.5233877e-06f);
  p = fmaf(p, wm, -4.39150654e-06f);
  p = fmaf(p, wm, 0.00021858087f);
  p = fmaf(p, wm, -0.00125372503f);
  p = fmaf(p, wm, -0.00417768164f);
  p = fmaf(p, wm, 0.246640727f);
  p = fmaf(p, wm, 1.50140941f);
  float tail = fmaf(1.0003f, __builtin_amdgcn_sqrtf(w), -0.1623f);
  p = (w < 5.0f) ? p : tail;
  return p * x;
}

// One _axis_mask's per-(b,s) params: split(K,3) -> k1(randint),k2(uniform start),k3(apply).
__device__ void axis_params(uint32_t K0, uint32_t K1, int dim, uint32_t span, uint32_t i,
                            int& start_out, int& end_out) {
  uint32_t k10, k11, k20, k21, k30, k31, a0, a1, b0, b1;
  tf2x32(K0, K1, 0u, 0u, k10, k11);   // k1
  tf2x32(K0, K1, 0u, 1u, k20, k21);   // k2
  tf2x32(K0, K1, 0u, 2u, k30, k31);   // k3
  tf2x32(k10, k11, 0u, 0u, a0, a1);   // randint internal split
  tf2x32(k10, k11, 0u, 1u, b0, b1);
  uint32_t hi = bits32(a0, a1, i);
  uint32_t lo = bits32(b0, b1, i);
  uint32_t mult = 65536u % span;
  mult = (mult * mult) % span;
  uint32_t off = ((hi % span) * mult + (lo % span)) % span;
  int width = 1 + (int)off;
  float u = u01(bits32(k20, k21, i));
  int M = dim - width; if (M < 1) M = 1;
  int start = (int)floorf(u * (float)M);
  bool apply = u01(bits32(k30, k31, i)) > 0.35f;
  start_out = start;
  end_out = apply ? (start + width) : start;   // empty interval when not applied
}

// Fallback (no workspace): full per-(b,s) params in one thread.
__device__ BSParams compute_params(uint32_t i) {
  BSParams p;
  uint32_t w0, w1;
  tf2x32(0u, 42u, 0u, 0u, w0, w1); axis_params(w0, w1, kT, kSpanT, i, p.ts1, p.te1);  // kt1
  tf2x32(0u, 42u, 0u, 1u, w0, w1); axis_params(w0, w1, kT, kSpanT, i, p.ts2, p.te2);  // kt2
  tf2x32(0u, 42u, 0u, 2u, w0, w1); axis_params(w0, w1, kF, kSpanF, i, p.fs1, p.fe1);  // kf1
  tf2x32(0u, 42u, 0u, 3u, w0, w1); axis_params(w0, w1, kF, kSpanF, i, p.fs2, p.fe2);  // kf2
  tf2x32(0u, 42u, 0u, 4u, w0, w1);                                                    // kn_a
  p.apply_n = (u01(bits32(w0, w1, i)) > 0.45f) ? 1 : 0;
  tf2x32(0u, 42u, 0u, 5u, p.kn0, p.kn1);                                              // kn
  tf2x32(0u, 42u, 0u, 6u, w0, w1);                                                    // ks_a
  bool apply_s = u01(bits32(w0, w1, i)) > 0.5f;
  tf2x32(0u, 42u, 0u, 7u, w0, w1);                                                    // ks
  float su = u01(bits32(w0, w1, i));
  float sc = fmaxf(0.85f, fmaf(su, 1.15f - 0.85f, 0.85f));
  p.scale = apply_s ? sc : 1.0f;
  return p;
}

// 4-wide parallel params: 1024 threads = 256 bs x 4 units; LDS combine.
__global__ __launch_bounds__(1024) void spec_params_kernel(BSParams* __restrict__ P) {
  __shared__ BSParams sp[kBS];
  __shared__ float ssc[kBS];
  __shared__ int ssa[kBS];
  const uint32_t bs = threadIdx.x & 255u;
  const uint32_t unit = threadIdx.x >> 8;   // 0..3
  uint32_t w0, w1;
  tf2x32(0u, 42u, 0u, unit, w0, w1);        // subkey for this unit's axis
  int s, e;
  if (unit < 2) axis_params(w0, w1, kT, kSpanT, bs, s, e);
  else          axis_params(w0, w1, kF, kSpanF, bs, s, e);
  if (unit == 0) { sp[bs].ts1 = s; sp[bs].te1 = e; }
  else if (unit == 1) { sp[bs].ts2 = s; sp[bs].te2 = e; }
  else if (unit == 2) { sp[bs].fs1 = s; sp[bs].fe1 = e; }
  else { sp[bs].fs2 = s; sp[bs].fe2 = e; }
  // cheap items spread one per unit
  if (unit == 0) {
    tf2x32(0u, 42u, 0u, 4u, w0, w1);                       // kn_a
    sp[bs].apply_n = (u01(bits32(w0, w1, bs)) > 0.45f) ? 1 : 0;
  } else if (unit == 1) {
    uint32_t n0, n1;
    tf2x32(0u, 42u, 0u, 5u, n0, n1);                       // kn
    sp[bs].kn0 = n0; sp[bs].kn1 = n1;
  } else if (unit == 2) {
    tf2x32(0u, 42u, 0u, 6u, w0, w1);                       // ks_a
    ssa[bs] = (u01(bits32(w0, w1, bs)) > 0.5f) ? 1 : 0;
  } else {
    tf2x32(0u, 42u, 0u, 7u, w0, w1);                       // ks
    float su = u01(bits32(w0, w1, bs));
    ssc[bs] = fmaxf(0.85f, fmaf(su, 1.15f - 0.85f, 0.85f));
  }
  __syncthreads();
  if (unit == 0) {
    sp[bs].scale = ssa[bs] ? ssc[bs] : 1.0f;
    P[bs] = sp[bs];
  }
}

// Round-4 structure: grid (32, 256), y = bs slowest (locality-preserving).
// Block covers 4096 elems of one (b,s) slice as 4 coalesced chunks of 1024;
// thread owns 4 floats per chunk (16 B/lane -> 1 KiB/wave per instruction).
// All 16 results accumulate in registers, then ONE batched nt+sc1 store.
template <bool USE_WS>
__global__ __launch_bounds__(256) void spec_main_kernel(const float* __restrict__ specs,
                                                        const int* __restrict__ mask,
                                                        float* __restrict__ out,
                                                        const BSParams* __restrict__ P) {
  const int bs = blockIdx.y;                           // 0..255
  const int block_off = blockIdx.x * 4096;             // within slice
  const int tid4 = threadIdx.x * 4;
  const long slice_base = (long)bs * kSlice;

  f32x4 a[4];
  long base[4];
#pragma unroll
  for (int k = 0; k < 4; ++k) {
    base[k] = slice_base + block_off + k * 1024 + tid4;
    a[k] = *reinterpret_cast<const f32x4*>(specs + base[k]);
  }
  float* o0 = out + base[0];
  float* o1 = out + base[1];
  float* o2 = out + base[2];
  float* o3 = out + base[3];

  if (mask[bs] == 0) {  // sensor off: pure passthrough (uniform per block)
    store4_nt_sc1(o0, a[0], o1, a[1], o2, a[2], o3, a[3]);
    return;
  }

  BSParams p;
  if (USE_WS) p = P[bs]; else p = compute_params((uint32_t)bs);

  // f-part of keep mask is chunk-invariant: off & 127 == tid4 & 127 for all chunks.
  const int f0 = tid4 & 127;
  int lo1 = min(4, max(0, p.fs1 - f0)), hi1 = min(4, max(0, p.fe1 - f0));
  int lo2 = min(4, max(0, p.fs2 - f0)), hi2 = min(4, max(0, p.fe2 - f0));
  uint32_t z1 = ((1u << hi1) - 1u) & ~((1u << lo1) - 1u);
  uint32_t z2 = ((1u << hi2) - 1u) & ~((1u << lo2) - 1u);
  const uint32_t fkeep = 0xFu & ~(z1 | z2);

  const int t0 = (block_off + tid4) >> 7;              // chunk k: t = t0 + 8k
  const float LO = __int_as_float(0xBF7FFFFF);         // nextafter(-1, 0)
  const float sc = p.scale;

  f32x4 r[4];

  if (p.apply_n) {   // uniform per block
#pragma unroll
    for (int k = 0; k < 4; ++k) {
      const int t = t0 + k * 8;
      const bool tm = !((t >= p.ts1) & (t < p.te1)) && !((t >= p.ts2) & (t < p.te2));
      const uint32_t keep = tm ? fkeep : 0u;
      const uint32_t c0 = (uint32_t)base[k];
      // data-independent noise first: overlaps threefry with in-flight loads
      float nv[4];
#pragma unroll
      for (int j = 0; j < 4; ++j) {
        const uint32_t bits = bits32(p.kn0, p.kn1, c0 + (uint32_t)j);
        float u1 = __uint_as_float(0x3f800000u | (bits >> 9));   // [1,2)
        float x = fmaxf(LO, fmaf(u1, 2.0f, -2.0f) + LO);         // == (u1-1)*2 + LO
        nv[j] = 0.08485281374f * erfinv_fast(x);                 // 0.06*sqrt(2)*erfinv
      }
      float v[4] = {a[k].x, a[k].y, a[k].z, a[k].w};
#pragma unroll
      for (int j = 0; j < 4; ++j) {
        float s = ((keep & (1u << j)) ? v[j] : 0.0f) + nv[j];
        s *= sc;
        v[j] = fminf(10.0f, fmaxf(-10.0f, s));
      }
      r[k] = f32x4{v[0], v[1], v[2], v[3]};
    }
  } else {
#pragma unroll
    for (int k = 0; k < 4; ++k) {
      const int t = t0 + k * 8;
      const bool tm = !((t >= p.ts1) & (t < p.te1)) && !((t >= p.ts2) & (t < p.te2));
      const uint32_t keep = tm ? fkeep : 0u;
      float v[4] = {a[k].x, a[k].y, a[k].z, a[k].w};
#pragma unroll
      for (int j = 0; j < 4; ++j) {
        float s = (keep & (1u << j)) ? v[j] : 0.0f;
        s *= sc;
        v[j] = fminf(10.0f, fmaxf(-10.0f, s));
      }
      r[k] = f32x4{v[0], v[1], v[2], v[3]};
    }
  }

  store4_nt_sc1(o0, r[0], o1, r[1], o2, r[2], o3, r[3]);
}

}  // namespace

extern "C" void kernel_launch(void* const* d_in, const int* in_sizes, int n_in,
                              void* d_out, int out_size, void* d_ws, size_t ws_size,
                              hipStream_t stream) {
  const float* specs = (const float*)d_in[0];
  const int* mask = (const int*)d_in[1];
  float* out = (float*)d_out;

  dim3 grid(kSlice / 4096, kBS);  // (32, 256), y = bs slowest
  dim3 block(256);

  if (ws_size >= sizeof(BSParams) * kBS) {
    BSParams* P = (BSParams*)d_ws;
    hipLaunchKernelGGL(spec_params_kernel, dim3(1), dim3(1024), 0, stream, P);
    hipLaunchKernelGGL((spec_main_kernel<true>), grid, block, 0, stream, specs, mask, out, P);
  } else {
    hipLaunchKernelGGL((spec_main_kernel<false>), grid, block, 0, stream, specs, mask, out,
                       (const BSParams*)nullptr);
  }
}